// Round 1
// baseline (153.706 us; speedup 1.0000x reference)
//
#include <hip/hip_runtime.h>

// PointPillars loss, MI355X.
// Dims fixed by setup_inputs(): B=16, C_cls=3, H=250, W=500, N=64 boxes/batch.
#define B_   16
#define NC_  3
#define H_   250
#define W_   500
#define N_   64
#define HW_  125000            // H_*W_
#define BHW_ 2000000           // B_*HW_
#define NBOX 1024              // B_*N_
#define TBL  2048              // LDS hash table slots (power of 2, >= NBOX)

// Workspace layout (uint32 words):
//   [0]  cls_sum   (float)
//   [1]  reg_sum   (float)
//   [2]  dir_sum   (float)
//   [3]  vm_count  (uint)
//   [4]  npos      (uint)
//   [16 .. 16+62500)            pos bit-plane (1 bit / cell, BHW_ bits)
//   [16+62500 .. 16+125000)     ign bit-plane
#define BITWORDS 62500
#define POS_OFF  16
#define IGN_OFF  (16 + BITWORDS)
#define WS_WORDS (16 + 2 * BITWORDS)

__global__ void init_ws(unsigned* __restrict__ ws) {
    int i = blockIdx.x * blockDim.x + threadIdx.x;
    if (i < WS_WORDS) ws[i] = 0u;
}

// One block, one thread per box. Builds pos/ign bit-planes, resolves per-cell
// winners (last-write-wins = highest flat box index, matching numpy scatter),
// and accumulates reg smooth-L1 and dir BCE sums + npos.
__global__ __launch_bounds__(NBOX) void box_kernel(
        const float* __restrict__ gt,
        const float* __restrict__ reg_pred,
        const float* __restrict__ dir_pred,
        unsigned* __restrict__ ws) {
    __shared__ unsigned keys[TBL];
    __shared__ unsigned maxv[TBL];
    __shared__ unsigned bins[TBL];
    const int tid = threadIdx.x;
    for (int s = tid; s < TBL; s += NBOX) {
        keys[s] = 0xFFFFFFFFu; maxv[s] = 0u; bins[s] = 0u;
    }
    __syncthreads();

    // gt_boxes: [B, N, 8] -> box tid at offset tid*8 (b-major, matches flat order)
    const float4* g4 = (const float4*)(gt + tid * 8);
    float4 p0 = g4[0], p1 = g4[1];
    float x = p0.x, y = p0.y, z = p0.z, l = p0.w;
    float w = p1.x, h = p1.y, rot = p1.z, cid = p1.w;

    bool valid = (cid == 0.0f) && (x >= 0.0f) && (x < 200.0f) &&
                 (y >= -50.0f) && (y < 50.0f);
    int gx = 0, gy = 0;
    if (valid) {
        gx = (int)floorf(x / 0.4f);            // SX = 0.4
        gy = (int)floorf((y + 50.0f) / 0.4f);  // SY = 0.4, Y_MIN = -50
        valid = (gx >= 0) && (gx < W_) && (gy >= 0) && (gy < H_);
    }
    const int b = tid >> 6;                    // tid / N_
    const int flat = b * HW_ + gy * W_ + gx;
    unsigned* posb = ws + POS_OFF;
    unsigned* ignb = ws + IGN_OFF;

    int slot = -1;
    if (valid) {
        atomicOr(&posb[flat >> 5], 1u << (flat & 31));
        // 3x3 ignore window (per-batch, bounds-clipped)
        for (int oy = -1; oy <= 1; ++oy) {
            int gy2 = gy + oy;
            if (gy2 < 0 || gy2 >= H_) continue;
            for (int ox = -1; ox <= 1; ++ox) {
                int gx2 = gx + ox;
                if (gx2 < 0 || gx2 >= W_) continue;
                int f2 = b * HW_ + gy2 * W_ + gx2;
                atomicOr(&ignb[f2 >> 5], 1u << (f2 & 31));
            }
        }
        // hash insert: key = flat cell id
        unsigned bin = (cosf(rot) >= 0.0f) ? 0u : 1u;
        unsigned key = (unsigned)flat;
        unsigned hsh = (key * 2654435761u) >> 21;   // 11 bits -> [0, 2048)
        for (;;) {
            unsigned old = atomicCAS(&keys[hsh], 0xFFFFFFFFu, key);
            if (old == 0xFFFFFFFFu || old == key) break;
            hsh = (hsh + 1u) & (TBL - 1u);
        }
        slot = (int)hsh;
        atomicMax(&maxv[slot], (unsigned)tid);
        atomicOr(&bins[slot], 1u << bin);
    }
    __syncthreads();

    if (valid && maxv[slot] == (unsigned)tid) {   // winner of its cell
        float cx = ((float)gx + 0.5f) * 0.4f;            // X_MIN = 0
        float cy = -50.0f + ((float)gy + 0.5f) * 0.4f;
        float tgt[7];
        tgt[0] = (x - cx) / 0.4f;
        tgt[1] = (y - cy) / 0.4f;
        tgt[2] = z;
        tgt[3] = logf(fmaxf(l, 1e-3f));
        tgt[4] = logf(fmaxf(w, 1e-3f));
        tgt[5] = logf(fmaxf(h, 1e-3f));
        tgt[6] = sinf(rot);
        const int pix = gy * W_ + gx;
        float reg_sum = 0.0f;
        #pragma unroll
        for (int c = 0; c < 7; ++c) {
            float d = fabsf(reg_pred[(b * 7 + c) * HW_ + pix] - tgt[c]);
            reg_sum += (d < 1.0f) ? 0.5f * d * d : (d - 0.5f);
        }
        unsigned u = bins[slot];                  // union of dir bins in this cell
        float dir_sum = 0.0f;
        #pragma unroll
        for (int c = 0; c < 2; ++c) {
            float xd = dir_pred[(b * 2 + c) * HW_ + pix];
            float t = (float)((u >> c) & 1u);
            dir_sum += fmaxf(xd, 0.0f) - xd * t + log1pf(expf(-fabsf(xd)));
        }
        float* facc = (float*)ws;
        atomicAdd(&facc[1], reg_sum);
        atomicAdd(&facc[2], dir_sum);
        atomicAdd(&ws[4], 1u);
    }
}

// Full pass over cls_pred [B,3,H,W] as float4. Channel planes (125000 elems)
// are 4-element aligned, so every float4 sits in one (b, ch) plane and its 4
// cells share one bit-plane word.
__global__ __launch_bounds__(256) void cls_kernel(
        const float* __restrict__ cls, unsigned* __restrict__ ws) {
    const unsigned* posb = ws + POS_OFF;
    const unsigned* ignb = ws + IGN_OFF;
    const int n4 = (B_ * NC_ * HW_) / 4;   // 1,500,000
    float sum = 0.0f;
    unsigned cnt = 0u;
    const int stride = gridDim.x * blockDim.x;
    for (int k = blockIdx.x * blockDim.x + threadIdx.x; k < n4; k += stride) {
        float4 v = ((const float4*)cls)[k];
        int e = k << 2;
        int bidx = e / (NC_ * HW_);
        int r    = e - bidx * (NC_ * HW_);
        int ch   = r / HW_;
        int pix  = r - ch * HW_;
        float xs[4] = {v.x, v.y, v.z, v.w};
        unsigned validm = 0xFu, posm = 0u;
        if (ch == 0) {
            int c = bidx * HW_ + pix;        // c % 4 == 0 -> 4 bits in one word
            unsigned pw = posb[c >> 5] >> (c & 31);
            unsigned iw = ignb[c >> 5] >> (c & 31);
            posm   = pw & 0xFu;
            validm = (~iw | pw) & 0xFu;      // (!ign) | pos
        }
        #pragma unroll
        for (int j = 0; j < 4; ++j) {
            if ((validm >> j) & 1u) {
                float x  = xs[j];
                bool pos = (posm >> j) & 1u;
                float ax = fabsf(x);
                float em = expf(-ax);
                float r1 = 1.0f / (1.0f + em);          // sigmoid(|x|)
                float p  = (x >= 0.0f) ? r1 : em * r1;  // sigmoid(x)
                float lg = log1pf(em);
                float t   = pos ? 1.0f : 0.0f;
                float bce = fmaxf(x, 0.0f) - x * t + lg;
                float omp = pos ? (1.0f - p) : p;       // 1 - p_t
                float at  = pos ? 0.25f : 0.75f;        // ALPHA
                sum += at * omp * omp * bce;            // GAMMA = 2
                cnt++;
            }
        }
    }
    // wave reduce (64 lanes) then cross-wave via LDS, one atomic pair / block
    #pragma unroll
    for (int off = 32; off > 0; off >>= 1) {
        sum += __shfl_down(sum, off, 64);
        cnt += __shfl_down(cnt, off, 64);
    }
    __shared__ float    ssum[4];
    __shared__ unsigned scnt[4];
    int lane = threadIdx.x & 63, wid = threadIdx.x >> 6;
    if (lane == 0) { ssum[wid] = sum; scnt[wid] = cnt; }
    __syncthreads();
    if (threadIdx.x == 0) {
        float    s = ssum[0] + ssum[1] + ssum[2] + ssum[3];
        unsigned c = scnt[0] + scnt[1] + scnt[2] + scnt[3];
        atomicAdd((float*)ws + 0, s);
        atomicAdd(ws + 3, c);
    }
}

__global__ void fin_kernel(const unsigned* __restrict__ ws, float* __restrict__ out) {
    if (blockIdx.x == 0 && threadIdx.x == 0) {
        const float* f = (const float*)ws;
        float vm   = (float)ws[3];
        float npos = (float)ws[4];
        float cls_loss = f[0] / fmaxf(vm, 1.0f);
        float reg_loss = f[1] / fmaxf(npos * 7.0f, 1.0f);
        float dir_loss = f[2] / fmaxf(npos * 2.0f, 1.0f);
        out[0] = 1.0f * cls_loss + 2.0f * reg_loss + 0.2f * dir_loss;  // W_CLS/W_REG/W_DIR
        out[1] = cls_loss;
        out[2] = reg_loss;
        out[3] = dir_loss;
    }
}

extern "C" void kernel_launch(void* const* d_in, const int* in_sizes, int n_in,
                              void* d_out, int out_size, void* d_ws, size_t ws_size,
                              hipStream_t stream) {
    const float* cls_pred = (const float*)d_in[0];
    const float* reg_pred = (const float*)d_in[1];
    const float* dir_pred = (const float*)d_in[2];
    const float* gt_boxes = (const float*)d_in[3];
    unsigned* ws = (unsigned*)d_ws;
    float* out = (float*)d_out;

    init_ws<<<(WS_WORDS + 255) / 256, 256, 0, stream>>>(ws);
    box_kernel<<<1, NBOX, 0, stream>>>(gt_boxes, reg_pred, dir_pred, ws);
    cls_kernel<<<1024, 256, 0, stream>>>(cls_pred, ws);
    fin_kernel<<<1, 64, 0, stream>>>(ws, out);
}